// Round 8
// baseline (263.833 us; speedup 1.0000x reference)
//
#include <hip/hip_runtime.h>

typedef unsigned short u16;
typedef unsigned int u32;
typedef __bf16 bf16x8 __attribute__((ext_vector_type(8)));
typedef float f32x4 __attribute__((ext_vector_type(4)));
typedef float f32x16 __attribute__((ext_vector_type(16)));
typedef int i32x2 __attribute__((ext_vector_type(2)));
typedef unsigned int u32x4 __attribute__((ext_vector_type(4)));

#define N_TOK 4096
#define DMODEL 1024
#define NH 16
#define DKH 64

__device__ inline u16 f2bf(float f){
  unsigned u = __float_as_uint(f);
  u += 0x7fffu + ((u >> 16) & 1u);
  return (u16)(u >> 16);
}

// raw v_exp_f32: args bounded (|x| < ~10), no libm guards needed
__device__ inline float fexp2(float x){ return __builtin_amdgcn_exp2f(x); }

// ---------- convert X (f32 -> bf16), vectorized ----------
__global__ __launch_bounds__(256) void k_convX(const float* __restrict__ X, u16* __restrict__ Xb){
  int i = blockIdx.x*256 + threadIdx.x;
  const float4 v = reinterpret_cast<const float4*>(X)[i];
  ushort4 o; o.x=f2bf(v.x); o.y=f2bf(v.y); o.z=f2bf(v.z); o.w=f2bf(v.w);
  reinterpret_cast<ushort4*>(Xb)[i] = o;
}

// ---------- transpose+convert W [1024][2048] f32 -> Wt [2048][1024] bf16 ----------
__global__ __launch_bounds__(256) void k_convW(const float* __restrict__ W, u16* __restrict__ Wt){
  __shared__ float tile[64][65];
  const int bn = blockIdx.x*64;
  const int bk = blockIdx.y*64;
  const int t = threadIdx.x;
  const int c4 = (t & 15)*4;
  const int r  = t >> 4;
  #pragma unroll
  for (int i=0;i<4;i++){
    int k = r + i*16;
    const float4 v = *reinterpret_cast<const float4*>(&W[(size_t)(bk+k)*2048 + bn + c4]);
    tile[k][c4+0]=v.x; tile[k][c4+1]=v.y; tile[k][c4+2]=v.z; tile[k][c4+3]=v.w;
  }
  __syncthreads();
  #pragma unroll
  for (int i=0;i<4;i++){
    int n = r + i*16;
    ushort4 o;
    o.x = f2bf(tile[c4+0][n]);
    o.y = f2bf(tile[c4+1][n]);
    o.z = f2bf(tile[c4+2][n]);
    o.w = f2bf(tile[c4+3][n]);
    *reinterpret_cast<ushort4*>(&Wt[(size_t)(bn+n)*1024 + bk + c4]) = o;
  }
}

// ---------- GEMM: proj[4096][2048] = Xb @ Wt^T, scatter to fragment-major Kf / Vf ----------
__global__ __launch_bounds__(256) void k_gemm(const u16* __restrict__ A, const u16* __restrict__ B,
                                              u16* __restrict__ kf_g, u16* __restrict__ vf_g){
  __shared__ alignas(16) u16 As[128*32];
  __shared__ alignas(16) u16 Bs[128*32];
  const int bm = blockIdx.y*128, bn = blockIdx.x*128;
  const int tid = threadIdx.x, wid = tid>>6, lane = tid&63;
  const int wr = wid>>1, wc = wid&1;
  const int lr = lane&15, lg = lane>>4;
  f32x4 acc[4][4] = {};

  for (int kk=0; kk<DMODEL; kk+=32){
    __syncthreads();
    #pragma unroll
    for (int i=0;i<2;i++){
      int chunk = (wid*2+i)*64 + lane;
      int row = chunk>>2, ko = (chunk&3)*8;
      const u16* ga = A + (size_t)(bm+row)*DMODEL + kk + ko;
      const u16* gb = B + (size_t)(bn+row)*DMODEL + kk + ko;
      __builtin_amdgcn_global_load_lds((const __attribute__((address_space(1))) void*)ga,
          (__attribute__((address_space(3))) void*)(&As[(wid*2+i)*512]), 16, 0, 0);
      __builtin_amdgcn_global_load_lds((const __attribute__((address_space(1))) void*)gb,
          (__attribute__((address_space(3))) void*)(&Bs[(wid*2+i)*512]), 16, 0, 0);
    }
    asm volatile("s_waitcnt vmcnt(0)" ::: "memory");
    __syncthreads();
    bf16x8 af[4], bfr[4];
    #pragma unroll
    for (int m=0;m<4;m++)
      af[m] = *reinterpret_cast<const bf16x8*>(&As[(wr*64+m*16+lr)*32 + lg*8]);
    #pragma unroll
    for (int n=0;n<4;n++)
      bfr[n] = *reinterpret_cast<const bf16x8*>(&Bs[(wc*64+n*16+lr)*32 + lg*8]);
    #pragma unroll
    for (int m=0;m<4;m++)
      #pragma unroll
      for (int n=0;n<4;n++)
        acc[m][n] = __builtin_amdgcn_mfma_f32_16x16x32_bf16(af[m], bfr[n], acc[m][n], 0,0,0);
  }

  #pragma unroll
  for (int m=0;m<4;m++){
    const int row0 = bm + wr*64 + m*16 + lg*4;
    #pragma unroll
    for (int n=0;n<4;n++){
      const int c = bn + wc*64 + n*16 + lr;
      if (c < DMODEL){
        const int hh = c>>6, d = c&63;
        const size_t base = ((size_t)hh*512 + (size_t)(row0>>5)*4 + (d>>4))*512;
        #pragma unroll
        for (int r=0;r<4;r++){
          const int row = row0 + r;
          kf_g[base + (size_t)(((row&31) | (((d>>3)&1)<<5)))*8 + (d&7)] = f2bf(acc[m][n][r]);
        }
      } else {
        const int cc = c - DMODEL; const int hh = cc>>6, d = cc&63;
        const size_t base = (((size_t)hh*64 + (row0>>6))*8 + (d>>5)*4 + ((row0>>4)&3))*512
                          + (size_t)(((d&31) | (((row0>>3)&1)<<5)))*8 + (row0&7);
        ushort4 o;
        o.x = f2bf(acc[m][n][0]); o.y = f2bf(acc[m][n][1]);
        o.z = f2bf(acc[m][n][2]); o.w = f2bf(acc[m][n][3]);
        *reinterpret_cast<ushort4*>(&vf_g[base]) = o;
      }
    }
  }
}

// scale a bf16x8 fragment by s (unpack, multiply, repack RNE)
__device__ inline bf16x8 scale_bf8(bf16x8 v, float s){
  u32x4 w = __builtin_bit_cast(u32x4, v);
  u32x4 r;
  #pragma unroll
  for (int i=0;i<4;i++){
    float lo = __uint_as_float(w[i] << 16) * s;
    float hi = __uint_as_float(w[i] & 0xffff0000u) * s;
    u32 p;
    asm("v_cvt_pk_bf16_f32 %0, %1, %2" : "=v"(p) : "v"(lo), "v"(hi));
    r[i] = p;
  }
  return __builtin_bit_cast(bf16x8, r);
}

// ---------- flash attention v8: late V loads (peak-reg cut -> 3 waves/SIMD), setprio on MFMA ----------
__global__ __launch_bounds__(256,3) void k_attn(const u16* __restrict__ kf_g, const u16* __restrict__ vf_g,
                                                float* __restrict__ out){
  __shared__ float comb[3][64][17];
  const int bid  = blockIdx.x;
  const int xcd  = bid & 7;
  const int slot = bid >> 3;
  const int h    = (xcd<<1) | (slot>>7);
  const int qt   = slot & 127;
  const int wid  = threadIdx.x >> 6;
  const int lane = threadIdx.x & 63;
  const int ql   = lane & 31;
  const int q0   = qt*32;
  const u16* __restrict__ Kfh = kf_g + (size_t)h*262144;
  const u16* __restrict__ Vfh = vf_g + (size_t)h*262144;
  const float SC = 0.18033688011112042f;   // log2(e)/sqrt(64)

  bf16x8 qb[4];
  #pragma unroll
  for (int ds=0; ds<4; ds++){
    bf16x8 raw = *reinterpret_cast<const bf16x8*>(&Kfh[(size_t)((q0>>5)*4 + ds)*512 + lane*8]);
    qb[ds] = scale_bf8(raw, SC);
  }

  f32x16 o0a = {}, o0b = {}, o1a = {}, o1b = {};
  float lp = 0.f;
  const int kb = wid*1024;

  bf16x8 kf[8];                      // single rotating buffer
  auto loadKhalf = [&](int kt, int half){
    const u16* kp = Kfh + ((size_t)(kt>>5)*4)*512 + lane*8;
    #pragma unroll
    for (int fi=0; fi<4; fi++)
      kf[half*4+fi] = *reinterpret_cast<const bf16x8*>(kp + (size_t)(half*4+fi)*512);
  };

  auto body = [&](int kt, int ktn){
    const u16* vb = Vfh + ((size_t)(kt>>6)*8)*512 + lane*8;

    // QK^T (swapped); rotate-prefetch next tile's K into regs just consumed
    f32x16 p0 = {}, p1 = {};
    __builtin_amdgcn_s_setprio(1);
    #pragma unroll
    for (int ds=0; ds<4; ds++) p0 = __builtin_amdgcn_mfma_f32_32x32x16_bf16(kf[ds],   qb[ds], p0, 0,0,0);
    __builtin_amdgcn_s_setprio(0);
    loadKhalf(ktn, 0);
    __builtin_amdgcn_s_setprio(1);
    #pragma unroll
    for (int ds=0; ds<4; ds++) p1 = __builtin_amdgcn_mfma_f32_32x32x16_bf16(kf[4+ds], qb[ds], p1, 0,0,0);
    __builtin_amdgcn_s_setprio(0);
    loadKhalf(ktn, 1);

    // vf0 issued here (covered by exp/pack of p0); vf1 later (covered by p1's)
    bf16x8 vf0[4];
    #pragma unroll
    for (int t=0; t<4; t++) vf0[t] = *reinterpret_cast<const bf16x8*>(vb + (size_t)t*512);

    // softmax p0 + pack pk0
    #pragma unroll
    for (int c=0; c<16; c++) p0[c] = fexp2(p0[c]);
    {
      float r0 = ((p0[0]+p0[1])+(p0[2]+p0[3])) + ((p0[4]+p0[5])+(p0[6]+p0[7]));
      float r1 = ((p0[8]+p0[9])+(p0[10]+p0[11])) + ((p0[12]+p0[13])+(p0[14]+p0[15]));
      lp += r0+r1;
    }
    u32 pk0[8];
    #pragma unroll
    for (int c2=0; c2<8; c2++){
      u32 a;
      asm("v_cvt_pk_bf16_f32 %0, %1, %2" : "=v"(a) : "v"(p0[2*c2]), "v"(p0[2*c2+1]));
      pk0[c2] = a;
    }

    bf16x8 vf1[4];
    #pragma unroll
    for (int t=0; t<4; t++) vf1[t] = *reinterpret_cast<const bf16x8*>(vb + (size_t)(4+t)*512);

    // softmax p1 + pack pk1
    #pragma unroll
    for (int c=0; c<16; c++) p1[c] = fexp2(p1[c]);
    {
      float r2 = ((p1[0]+p1[1])+(p1[2]+p1[3])) + ((p1[4]+p1[5])+(p1[6]+p1[7]));
      float r3 = ((p1[8]+p1[9])+(p1[10]+p1[11])) + ((p1[12]+p1[13])+(p1[14]+p1[15]));
      lp += r2+r3;
    }
    u32 pk1[8];
    #pragma unroll
    for (int c2=0; c2<8; c2++){
      u32 b;
      asm("v_cvt_pk_bf16_f32 %0, %1, %2" : "=v"(b) : "v"(p1[2*c2]), "v"(p1[2*c2+1]));
      pk1[c2] = b;
    }

    // PV (swapped), split accumulators
    #pragma unroll
    for (int t=0; t<4; t++){
      const u32* pks = (t>>1) ? pk1 : pk0;
      const int base = 4*(t&1);
      i32x2 r0s = __builtin_amdgcn_permlane32_swap((int)pks[base+0], (int)pks[base+2], false, false);
      i32x2 r1s = __builtin_amdgcn_permlane32_swap((int)pks[base+1], (int)pks[base+3], false, false);
      u32x4 w; w[0] = (u32)r0s[0]; w[1] = (u32)r1s[0]; w[2] = (u32)r0s[1]; w[3] = (u32)r1s[1];
      bf16x8 bt = __builtin_bit_cast(bf16x8, w);
      __builtin_amdgcn_s_setprio(1);
      if (t & 1){
        o0b = __builtin_amdgcn_mfma_f32_32x32x16_bf16(vf0[t], bt, o0b, 0,0,0);
        o1b = __builtin_amdgcn_mfma_f32_32x32x16_bf16(vf1[t], bt, o1b, 0,0,0);
      } else {
        o0a = __builtin_amdgcn_mfma_f32_32x32x16_bf16(vf0[t], bt, o0a, 0,0,0);
        o1a = __builtin_amdgcn_mfma_f32_32x32x16_bf16(vf1[t], bt, o1a, 0,0,0);
      }
      __builtin_amdgcn_s_setprio(0);
    }
  };

  loadKhalf(kb, 0); loadKhalf(kb, 1);
  for (int it=0; it<16; ++it){
    const int kt  = kb + (it<<6);
    const int ktn = kb + (((it+1)&15)<<6);   // last body re-prefetches tile 0 (L2-hot, harmless)
    body(kt, ktn);
  }

  f32x16 o0 = o0a + o0b, o1 = o1a + o1b;
  lp += __shfl_xor(lp, 32, 64);

  // two-phase split-K combine (13 KB LDS)
  if (wid){
    float* c = &comb[wid-1][lane][0];
    #pragma unroll
    for (int g=0; g<16; g++) c[g] = o0[g];
    c[16] = lp;
  }
  __syncthreads();
  if (!wid){
    #pragma unroll
    for (int w=0; w<3; w++){
      const float* c = &comb[w][lane][0];
      #pragma unroll
      for (int g=0; g<16; g++) o0[g] += c[g];
      lp += c[16];
    }
  }
  __syncthreads();
  if (wid){
    float* c = &comb[wid-1][lane][0];
    #pragma unroll
    for (int g=0; g<16; g++) c[g] = o1[g];
  }
  __syncthreads();
  if (!wid){
    #pragma unroll
    for (int w=0; w<3; w++){
      const float* c = &comb[w][lane][0];
      #pragma unroll
      for (int g=0; g<16; g++) o1[g] += c[g];
    }
    const int hi = lane >> 5;
    const float inv = 1.f / lp;
    float* orow = out + (size_t)(q0 + ql)*DMODEL + h*DKH;
    #pragma unroll
    for (int g=0; g<4; g++){
      float4 s0, s1;
      s0.x = o0[4*g+0]*inv; s0.y = o0[4*g+1]*inv; s0.z = o0[4*g+2]*inv; s0.w = o0[4*g+3]*inv;
      s1.x = o1[4*g+0]*inv; s1.y = o1[4*g+1]*inv; s1.z = o1[4*g+2]*inv; s1.w = o1[4*g+3]*inv;
      *reinterpret_cast<float4*>(&orow[      8*g + 4*hi]) = s0;
      *reinterpret_cast<float4*>(&orow[32 +  8*g + 4*hi]) = s1;
    }
  }
}

extern "C" void kernel_launch(void* const* d_in, const int* in_sizes, int n_in,
                              void* d_out, int out_size, void* d_ws, size_t ws_size,
                              hipStream_t stream) {
  const float* X = (const float*)d_in[0];
  const float* W = (const float*)d_in[1];
  float* out = (float*)d_out;
  u16* Xb = (u16*)d_ws;                         //  8 MB
  u16* Wt = Xb + (size_t)N_TOK*DMODEL;          //  4 MB
  u16* Kf = Wt + (size_t)2*DMODEL*DMODEL;       //  8 MB fragment-major K/Q
  u16* Vf = Kf + (size_t)N_TOK*DMODEL;          //  8 MB fragment-major V^T

  k_convX<<<dim3(4096), dim3(256), 0, stream>>>(X, Xb);
  k_convW<<<dim3(32,16), dim3(256), 0, stream>>>(W, Wt);
  k_gemm <<<dim3(16,32), dim3(256), 0, stream>>>(Xb, Wt, Kf, Vf);
  k_attn <<<dim3(2048), dim3(256), 0, stream>>>(Kf, Vf, out);
}

// Round 9
// 132.024 us; speedup vs baseline: 1.9984x; 1.9984x over previous
//
#include <hip/hip_runtime.h>

typedef unsigned short u16;
typedef unsigned int u32;
typedef __bf16 bf16x8 __attribute__((ext_vector_type(8)));
typedef float f32x4 __attribute__((ext_vector_type(4)));
typedef float f32x16 __attribute__((ext_vector_type(16)));
typedef int i32x2 __attribute__((ext_vector_type(2)));
typedef unsigned int u32x4 __attribute__((ext_vector_type(4)));

#define N_TOK 4096
#define DMODEL 1024
#define NH 16
#define DKH 64

__device__ inline u16 f2bf(float f){
  unsigned u = __float_as_uint(f);
  u += 0x7fffu + ((u >> 16) & 1u);
  return (u16)(u >> 16);
}

// raw v_exp_f32: args bounded (|x| < ~10), no libm guards needed
__device__ inline float fexp2(float x){ return __builtin_amdgcn_exp2f(x); }

// ---------- convert X (f32 -> bf16), vectorized ----------
__global__ __launch_bounds__(256) void k_convX(const float* __restrict__ X, u16* __restrict__ Xb){
  int i = blockIdx.x*256 + threadIdx.x;
  const float4 v = reinterpret_cast<const float4*>(X)[i];
  ushort4 o; o.x=f2bf(v.x); o.y=f2bf(v.y); o.z=f2bf(v.z); o.w=f2bf(v.w);
  reinterpret_cast<ushort4*>(Xb)[i] = o;
}

// ---------- transpose+convert W [1024][2048] f32 -> Wt [2048][1024] bf16 ----------
__global__ __launch_bounds__(256) void k_convW(const float* __restrict__ W, u16* __restrict__ Wt){
  __shared__ float tile[64][65];
  const int bn = blockIdx.x*64;
  const int bk = blockIdx.y*64;
  const int t = threadIdx.x;
  const int c4 = (t & 15)*4;
  const int r  = t >> 4;
  #pragma unroll
  for (int i=0;i<4;i++){
    int k = r + i*16;
    const float4 v = *reinterpret_cast<const float4*>(&W[(size_t)(bk+k)*2048 + bn + c4]);
    tile[k][c4+0]=v.x; tile[k][c4+1]=v.y; tile[k][c4+2]=v.z; tile[k][c4+3]=v.w;
  }
  __syncthreads();
  #pragma unroll
  for (int i=0;i<4;i++){
    int n = r + i*16;
    ushort4 o;
    o.x = f2bf(tile[c4+0][n]);
    o.y = f2bf(tile[c4+1][n]);
    o.z = f2bf(tile[c4+2][n]);
    o.w = f2bf(tile[c4+3][n]);
    *reinterpret_cast<ushort4*>(&Wt[(size_t)(bn+n)*1024 + bk + c4]) = o;
  }
}

// ---------- GEMM v2: BK=64, source-swizzled staging (linear LDS dest, XOR'd global chunk),
// XOR'd ds_read -> conflict-free [128][64] tiles. Scatter epilogue unchanged. ----------
__global__ __launch_bounds__(256) void k_gemm(const u16* __restrict__ A, const u16* __restrict__ B,
                                              u16* __restrict__ kf_g, u16* __restrict__ vf_g){
  __shared__ alignas(16) u16 As[128*64];
  __shared__ alignas(16) u16 Bs[128*64];
  const int bm = blockIdx.y*128, bn = blockIdx.x*128;
  const int tid = threadIdx.x, wid = tid>>6, lane = tid&63;
  const int wr = wid>>1, wc = wid&1;
  const int lr = lane&15, lg = lane>>4;
  f32x4 acc[4][4] = {};

  for (int kk=0; kk<DMODEL; kk+=64){
    __syncthreads();
    #pragma unroll
    for (int i=0;i<4;i++){
      const int chunk = (wid*4+i)*64 + lane;          // 0..1023, 16B each
      const int row = chunk>>3, koc = chunk&7;
      const int swz = koc ^ (row&7);                  // pre-swizzle SOURCE; LDS dest linear
      const u16* ga = A + (size_t)(bm+row)*DMODEL + kk + swz*8;
      const u16* gb = B + (size_t)(bn+row)*DMODEL + kk + swz*8;
      __builtin_amdgcn_global_load_lds((const __attribute__((address_space(1))) void*)ga,
          (__attribute__((address_space(3))) void*)(&As[(size_t)chunk*8]), 16, 0, 0);
      __builtin_amdgcn_global_load_lds((const __attribute__((address_space(1))) void*)gb,
          (__attribute__((address_space(3))) void*)(&Bs[(size_t)chunk*8]), 16, 0, 0);
    }
    asm volatile("s_waitcnt vmcnt(0)" ::: "memory");
    __syncthreads();
    #pragma unroll
    for (int ks=0; ks<2; ks++){
      bf16x8 af[4], bfr[4];
      #pragma unroll
      for (int m=0;m<4;m++){
        const int row = wr*64+m*16+lr, cr = ks*4+lg;
        af[m] = *reinterpret_cast<const bf16x8*>(&As[(size_t)(row*8 + (cr ^ (row&7)))*8]);
      }
      #pragma unroll
      for (int n=0;n<4;n++){
        const int row = wc*64+n*16+lr, cr = ks*4+lg;
        bfr[n] = *reinterpret_cast<const bf16x8*>(&Bs[(size_t)(row*8 + (cr ^ (row&7)))*8]);
      }
      #pragma unroll
      for (int m=0;m<4;m++)
        #pragma unroll
        for (int n=0;n<4;n++)
          acc[m][n] = __builtin_amdgcn_mfma_f32_16x16x32_bf16(af[m], bfr[n], acc[m][n], 0,0,0);
    }
  }

  #pragma unroll
  for (int m=0;m<4;m++){
    const int row0 = bm + wr*64 + m*16 + lg*4;
    #pragma unroll
    for (int n=0;n<4;n++){
      const int c = bn + wc*64 + n*16 + lr;
      if (c < DMODEL){
        const int hh = c>>6, d = c&63;
        const size_t base = ((size_t)hh*512 + (size_t)(row0>>5)*4 + (d>>4))*512;
        #pragma unroll
        for (int r=0;r<4;r++){
          const int row = row0 + r;
          kf_g[base + (size_t)(((row&31) | (((d>>3)&1)<<5)))*8 + (d&7)] = f2bf(acc[m][n][r]);
        }
      } else {
        const int cc = c - DMODEL; const int hh = cc>>6, d = cc&63;
        const size_t base = (((size_t)hh*64 + (row0>>6))*8 + (d>>5)*4 + ((row0>>4)&3))*512
                          + (size_t)(((d&31) | (((row0>>3)&1)<<5)))*8 + (row0&7);
        ushort4 o;
        o.x = f2bf(acc[m][n][0]); o.y = f2bf(acc[m][n][1]);
        o.z = f2bf(acc[m][n][2]); o.w = f2bf(acc[m][n][3]);
        *reinterpret_cast<ushort4*>(&vf_g[base]) = o;
      }
    }
  }
}

// scale a bf16x8 fragment by s (unpack, multiply, repack RNE)
__device__ inline bf16x8 scale_bf8(bf16x8 v, float s){
  u32x4 w = __builtin_bit_cast(u32x4, v);
  u32x4 r;
  #pragma unroll
  for (int i=0;i<4;i++){
    float lo = __uint_as_float(w[i] << 16) * s;
    float hi = __uint_as_float(w[i] & 0xffff0000u) * s;
    u32 p;
    asm("v_cvt_pk_bf16_f32 %0, %1, %2" : "=v"(p) : "v"(lo), "v"(hi));
    r[i] = p;
  }
  return __builtin_bit_cast(bf16x8, r);
}

// ---------- flash attention: round-7 body verbatim (proven 97.5us), launch_bounds (256,2) ----------
__global__ __launch_bounds__(256,2) void k_attn(const u16* __restrict__ kf_g, const u16* __restrict__ vf_g,
                                                float* __restrict__ out){
  __shared__ float comb[3][64][17];
  const int bid  = blockIdx.x;
  const int xcd  = bid & 7;
  const int slot = bid >> 3;
  const int h    = (xcd<<1) | (slot>>7);
  const int qt   = slot & 127;
  const int wid  = threadIdx.x >> 6;
  const int lane = threadIdx.x & 63;
  const int ql   = lane & 31;
  const int q0   = qt*32;
  const u16* __restrict__ Kfh = kf_g + (size_t)h*262144;
  const u16* __restrict__ Vfh = vf_g + (size_t)h*262144;
  const float SC = 0.18033688011112042f;   // log2(e)/sqrt(64)

  bf16x8 qb[4];
  #pragma unroll
  for (int ds=0; ds<4; ds++){
    bf16x8 raw = *reinterpret_cast<const bf16x8*>(&Kfh[(size_t)((q0>>5)*4 + ds)*512 + lane*8]);
    qb[ds] = scale_bf8(raw, SC);
  }

  // split PV accumulators: t&1 -> b, else a (intra-body chain depth 2 per accumulator)
  f32x16 o0a = {}, o0b = {}, o1a = {}, o1b = {};
  float lp = 0.f;
  const int kb = wid*1024;

  bf16x8 kf[8];                      // single rotating buffer
  auto loadKhalf = [&](int kt, int half){
    const u16* kp = Kfh + ((size_t)(kt>>5)*4)*512 + lane*8;
    #pragma unroll
    for (int fi=0; fi<4; fi++)
      kf[half*4+fi] = *reinterpret_cast<const bf16x8*>(kp + (size_t)(half*4+fi)*512);
  };

  auto body = [&](int kt, int ktn){
    // V fragments for this tile (issued early, consumed after softmax)
    const u16* vb = Vfh + ((size_t)(kt>>6)*8)*512 + lane*8;
    bf16x8 vf0[4], vf1[4];
    #pragma unroll
    for (int t=0; t<4; t++){
      vf0[t] = *reinterpret_cast<const bf16x8*>(vb + (size_t)t*512);
      vf1[t] = *reinterpret_cast<const bf16x8*>(vb + (size_t)(4+t)*512);
    }
    // QK^T (swapped); rotate-prefetch next tile's K into the regs just consumed
    f32x16 p0 = {}, p1 = {};
    #pragma unroll
    for (int ds=0; ds<4; ds++) p0 = __builtin_amdgcn_mfma_f32_32x32x16_bf16(kf[ds],   qb[ds], p0, 0,0,0);
    loadKhalf(ktn, 0);   // kf[0..3] dead after p0 chain issued (anti-dep keeps order)
    #pragma unroll
    for (int ds=0; ds<4; ds++) p1 = __builtin_amdgcn_mfma_f32_32x32x16_bf16(kf[4+ds], qb[ds], p1, 0,0,0);
    loadKhalf(ktn, 1);   // kf[4..7]

    // static-normalizer softmax (Q prescaled by SC)
    #pragma unroll
    for (int c=0; c<16; c++){
      p0[c] = fexp2(p0[c]);
      p1[c] = fexp2(p1[c]);
    }
    // scalar l accumulation (balanced tree; off PV critical path)
    {
      float r0 = ((p0[0]+p0[1])+(p0[2]+p0[3])) + ((p0[4]+p0[5])+(p0[6]+p0[7]));
      float r1 = ((p0[8]+p0[9])+(p0[10]+p0[11])) + ((p0[12]+p0[13])+(p0[14]+p0[15]));
      float r2 = ((p1[0]+p1[1])+(p1[2]+p1[3])) + ((p1[4]+p1[5])+(p1[6]+p1[7]));
      float r3 = ((p1[8]+p1[9])+(p1[10]+p1[11])) + ((p1[12]+p1[13])+(p1[14]+p1[15]));
      lp += (r0+r1)+(r2+r3);
    }

    u32 pk0[8], pk1[8];
    #pragma unroll
    for (int c2=0; c2<8; c2++){
      u32 a, b;
      asm("v_cvt_pk_bf16_f32 %0, %1, %2" : "=v"(a) : "v"(p0[2*c2]), "v"(p0[2*c2+1]));
      asm("v_cvt_pk_bf16_f32 %0, %1, %2" : "=v"(b) : "v"(p1[2*c2]), "v"(p1[2*c2+1]));
      pk0[c2] = a; pk1[c2] = b;
    }
    #pragma unroll
    for (int t=0; t<4; t++){
      const u32* pks = (t>>1) ? pk1 : pk0;
      const int base = 4*(t&1);
      i32x2 r0s = __builtin_amdgcn_permlane32_swap((int)pks[base+0], (int)pks[base+2], false, false);
      i32x2 r1s = __builtin_amdgcn_permlane32_swap((int)pks[base+1], (int)pks[base+3], false, false);
      u32x4 w; w[0] = (u32)r0s[0]; w[1] = (u32)r1s[0]; w[2] = (u32)r0s[1]; w[3] = (u32)r1s[1];
      bf16x8 bt = __builtin_bit_cast(bf16x8, w);
      if (t & 1){
        o0b = __builtin_amdgcn_mfma_f32_32x32x16_bf16(vf0[t], bt, o0b, 0,0,0);
        o1b = __builtin_amdgcn_mfma_f32_32x32x16_bf16(vf1[t], bt, o1b, 0,0,0);
      } else {
        o0a = __builtin_amdgcn_mfma_f32_32x32x16_bf16(vf0[t], bt, o0a, 0,0,0);
        o1a = __builtin_amdgcn_mfma_f32_32x32x16_bf16(vf1[t], bt, o1a, 0,0,0);
      }
    }
  };

  loadKhalf(kb, 0); loadKhalf(kb, 1);
  for (int it=0; it<16; ++it){
    const int kt  = kb + (it<<6);
    const int ktn = kb + (((it+1)&15)<<6);   // last body re-prefetches tile 0 (L2-hot, harmless)
    body(kt, ktn);
  }

  f32x16 o0 = o0a + o0b, o1 = o1a + o1b;
  lp += __shfl_xor(lp, 32, 64);

  // two-phase split-K combine (13 KB LDS)
  if (wid){
    float* c = &comb[wid-1][lane][0];
    #pragma unroll
    for (int g=0; g<16; g++) c[g] = o0[g];
    c[16] = lp;
  }
  __syncthreads();
  if (!wid){
    #pragma unroll
    for (int w=0; w<3; w++){
      const float* c = &comb[w][lane][0];
      #pragma unroll
      for (int g=0; g<16; g++) o0[g] += c[g];
      lp += c[16];
    }
  }
  __syncthreads();
  if (wid){
    float* c = &comb[wid-1][lane][0];
    #pragma unroll
    for (int g=0; g<16; g++) c[g] = o1[g];
  }
  __syncthreads();
  if (!wid){
    #pragma unroll
    for (int w=0; w<3; w++){
      const float* c = &comb[w][lane][0];
      #pragma unroll
      for (int g=0; g<16; g++) o1[g] += c[g];
    }
    const int hi = lane >> 5;
    const float inv = 1.f / lp;
    float* orow = out + (size_t)(q0 + ql)*DMODEL + h*DKH;
    #pragma unroll
    for (int g=0; g<4; g++){
      float4 s0, s1;
      s0.x = o0[4*g+0]*inv; s0.y = o0[4*g+1]*inv; s0.z = o0[4*g+2]*inv; s0.w = o0[4*g+3]*inv;
      s1.x = o1[4*g+0]*inv; s1.y = o1[4*g+1]*inv; s1.z = o1[4*g+2]*inv; s1.w = o1[4*g+3]*inv;
      *reinterpret_cast<float4*>(&orow[      8*g + 4*hi]) = s0;
      *reinterpret_cast<float4*>(&orow[32 +  8*g + 4*hi]) = s1;
    }
  }
}

extern "C" void kernel_launch(void* const* d_in, const int* in_sizes, int n_in,
                              void* d_out, int out_size, void* d_ws, size_t ws_size,
                              hipStream_t stream) {
  const float* X = (const float*)d_in[0];
  const float* W = (const float*)d_in[1];
  float* out = (float*)d_out;
  u16* Xb = (u16*)d_ws;                         //  8 MB
  u16* Wt = Xb + (size_t)N_TOK*DMODEL;          //  4 MB
  u16* Kf = Wt + (size_t)2*DMODEL*DMODEL;       //  8 MB fragment-major K/Q
  u16* Vf = Kf + (size_t)N_TOK*DMODEL;          //  8 MB fragment-major V^T

  k_convX<<<dim3(4096), dim3(256), 0, stream>>>(X, Xb);
  k_convW<<<dim3(32,16), dim3(256), 0, stream>>>(W, Wt);
  k_gemm <<<dim3(16,32), dim3(256), 0, stream>>>(Xb, Wt, Kf, Vf);
  k_attn <<<dim3(2048), dim3(256), 0, stream>>>(Kf, Vf, out);
}